// Round 2
// baseline (515.511 us; speedup 1.0000x reference)
//
#include <hip/hip_runtime.h>
#include <hip/hip_bf16.h>
#include <math.h>

// Problem constants
#define NHD 8
#define DH 32
#define CC 256
#define NTOK 4096
#define BATCH 4
#define MTOT 16384

typedef __attribute__((ext_vector_type(8))) short short8;
typedef __attribute__((ext_vector_type(4))) float f32x4;

__device__ inline float bf2f(short s) {
    unsigned int u = ((unsigned int)(unsigned short)s) << 16;
    float f; __builtin_memcpy(&f, &u, 4); return f;
}
__device__ inline short f2bf(float f) {
    __hip_bfloat16 h = __float2bfloat16(f);
    unsigned short u; __builtin_memcpy(&u, &h, 2); return (short)u;
}

// ---------------- conversion kernels ----------------
__global__ __launch_bounds__(256) void conv_x_kernel(const float* __restrict__ src,
                                                     short* __restrict__ dst, int n8) {
    int t = blockIdx.x * 256 + threadIdx.x;
    if (t >= n8) return;
    const f32x4* s4 = (const f32x4*)src;
    f32x4 a = s4[t * 2], b = s4[t * 2 + 1];
    short8 o;
    o[0] = f2bf(a[0]); o[1] = f2bf(a[1]); o[2] = f2bf(a[2]); o[3] = f2bf(a[3]);
    o[4] = f2bf(b[0]); o[5] = f2bf(b[1]); o[6] = f2bf(b[2]); o[7] = f2bf(b[3]);
    ((short8*)dst)[t] = o;
}

__global__ __launch_bounds__(256) void conv_w_kernel(const float* __restrict__ Wq,
                                                     const float* __restrict__ Wk,
                                                     const float* __restrict__ Wv,
                                                     const float* __restrict__ Wo,
                                                     short* __restrict__ dst) {
    int w = blockIdx.y;
    const float* src = (w == 0) ? Wq : (w == 1) ? Wk : (w == 2) ? Wv : Wo;
    int t = blockIdx.x * 256 + threadIdx.x;   // 32 blocks * 256 = 8192 threads, 8 elems each
    const f32x4* s4 = (const f32x4*)src;
    f32x4 a = s4[t * 2], b = s4[t * 2 + 1];
    short8 o;
    o[0] = f2bf(a[0]); o[1] = f2bf(a[1]); o[2] = f2bf(a[2]); o[3] = f2bf(a[3]);
    o[4] = f2bf(b[0]); o[5] = f2bf(b[1]); o[6] = f2bf(b[2]); o[7] = f2bf(b[3]);
    ((short8*)(dst + w * 65536))[t] = o;
}

// ---------------- QKV projection GEMM ----------------
// y = x @ W^T + b.  A = x[m][k] bf16, B^T = W[j][k] bf16 (torch Linear layout, k-contiguous).
// Grid: (256 row-blocks of 64, 3 weights). 4 waves/block, each wave: 16 rows x 256 cols.
__global__ __launch_bounds__(256) void qkv_kernel(const short* __restrict__ xb,
                                                  const short* __restrict__ Wb,
                                                  const float* __restrict__ bq,
                                                  const float* __restrict__ bk,
                                                  const float* __restrict__ bv,
                                                  short* __restrict__ Qb,
                                                  short* __restrict__ Kb,
                                                  short* __restrict__ Vt,
                                                  short* __restrict__ Vres) {
    int wsel = blockIdx.y;
    const short* W = Wb + wsel * 65536;
    int wave = threadIdx.x >> 6;
    int lane = threadIdx.x & 63;
    int lo = lane & 15, hi = lane >> 4;
    int m0 = blockIdx.x * 64 + wave * 16;

    f32x4 acc[16];
#pragma unroll
    for (int i = 0; i < 16; i++) acc[i] = (f32x4){0, 0, 0, 0};

    for (int ks = 0; ks < 8; ks++) {
        short8 a = *(const short8*)(xb + (m0 + lo) * 256 + ks * 32 + hi * 8);
#pragma unroll
        for (int nf = 0; nf < 16; nf++) {
            short8 b = *(const short8*)(W + (nf * 16 + lo) * 256 + ks * 32 + hi * 8);
            acc[nf] = __builtin_amdgcn_mfma_f32_16x16x32_bf16(a, b, acc[nf], 0, 0, 0);
        }
    }
    const float* bias = (wsel == 0) ? bq : (wsel == 1) ? bk : bv;
#pragma unroll
    for (int nf = 0; nf < 16; nf++) {
#pragma unroll
        for (int r = 0; r < 4; r++) {
            int m = m0 + hi * 4 + r;
            int c = nf * 16 + lo;
            short s = f2bf(acc[nf][r] + bias[c]);
            int bb = m >> 12, n = m & 4095;
            int h = c >> 5, d = c & 31;
            int bh = bb * 8 + h;
            if (wsel == 0)      Qb[(bh * 4096 + n) * 32 + d] = s;
            else if (wsel == 1) Kb[(bh * 4096 + n) * 32 + d] = s;
            else {
                Vt[(bh * 32 + d) * 4096 + n] = s;   // transposed per head for PV B-operand
                Vres[m * 256 + c] = s;              // row-major for residual
            }
        }
    }
}

// ---------------- flash attention ----------------
// Grid: 32 (b,h) * 64 q-blocks = 2048 WGs. 4 waves, wave owns 16 q-rows. KV tile = 64.
__global__ __launch_bounds__(256) void attn_kernel(const short* __restrict__ Qb,
                                                   const short* __restrict__ Kb,
                                                   const short* __restrict__ Vt,
                                                   short* __restrict__ O) {
    __shared__ short Pl[4][16][104];   // per-wave P tile, padded stride (208B, 16B-aligned)
    int bx = blockIdx.x;
    int bh = bx >> 6;
    int qb = bx & 63;
    int wave = threadIdx.x >> 6, lane = threadIdx.x & 63;
    int lo = lane & 15, hi = lane >> 4;
    int q0 = qb * 64 + wave * 16;

    short8 aq = *(const short8*)(Qb + (bh * 4096 + q0 + lo) * 32 + hi * 8);

    float mr[4], lr[4];
    f32x4 oacc[2];
#pragma unroll
    for (int r = 0; r < 4; r++) { mr[r] = -1e30f; lr[r] = 0.f; }
    oacc[0] = (f32x4){0, 0, 0, 0};
    oacc[1] = (f32x4){0, 0, 0, 0};

    const float kScale = 0.17677669529663687f;  // 1/sqrt(32)
    const short* Kbase = Kb + bh * 131072;
    const short* Vbase = Vt + bh * 131072;

    for (int kv = 0; kv < 4096; kv += 64) {
        f32x4 s[4];
#pragma unroll
        for (int cf = 0; cf < 4; cf++) {
            short8 bk_ = *(const short8*)(Kbase + (kv + cf * 16 + lo) * 32 + hi * 8);
            f32x4 z = (f32x4){0, 0, 0, 0};
            s[cf] = __builtin_amdgcn_mfma_f32_16x16x32_bf16(aq, bk_, z, 0, 0, 0);
        }
#pragma unroll
        for (int cf = 0; cf < 4; cf++)
#pragma unroll
            for (int r = 0; r < 4; r++) s[cf][r] *= kScale;

        float mx[4];
#pragma unroll
        for (int r = 0; r < 4; r++)
            mx[r] = fmaxf(fmaxf(s[0][r], s[1][r]), fmaxf(s[2][r], s[3][r]));
#pragma unroll
        for (int d = 1; d < 16; d <<= 1)
#pragma unroll
            for (int r = 0; r < 4; r++) mx[r] = fmaxf(mx[r], __shfl_xor(mx[r], d, 64));

        float mnew[4], al[4];
#pragma unroll
        for (int r = 0; r < 4; r++) {
            mnew[r] = fmaxf(mr[r], mx[r]);
            al[r] = __expf(mr[r] - mnew[r]);
            mr[r] = mnew[r];
            lr[r] *= al[r];
        }
        float p[4][4];
#pragma unroll
        for (int cf = 0; cf < 4; cf++)
#pragma unroll
            for (int r = 0; r < 4; r++) p[cf][r] = __expf(s[cf][r] - mnew[r]);

        float rs[4];
#pragma unroll
        for (int r = 0; r < 4; r++) rs[r] = p[0][r] + p[1][r] + p[2][r] + p[3][r];
#pragma unroll
        for (int d = 1; d < 16; d <<= 1)
#pragma unroll
            for (int r = 0; r < 4; r++) rs[r] += __shfl_xor(rs[r], d, 64);
#pragma unroll
        for (int r = 0; r < 4; r++) lr[r] += rs[r];

#pragma unroll
        for (int nf = 0; nf < 2; nf++)
#pragma unroll
            for (int r = 0; r < 4; r++) oacc[nf][r] *= al[r];

        // P -> LDS (wave-private region; same-wave RAW ordered by compiler lgkmcnt)
#pragma unroll
        for (int cf = 0; cf < 4; cf++)
#pragma unroll
            for (int r = 0; r < 4; r++)
                Pl[wave][hi * 4 + r][cf * 16 + lo] = f2bf(p[cf][r]);

#pragma unroll
        for (int nf = 0; nf < 2; nf++) {
#pragma unroll
            for (int kf = 0; kf < 2; kf++) {
                short8 ap = *(const short8*)(&Pl[wave][lo][kf * 32 + hi * 8]);
                short8 bv_ = *(const short8*)(Vbase + (nf * 16 + lo) * 4096 + kv + kf * 32 + hi * 8);
                oacc[nf] = __builtin_amdgcn_mfma_f32_16x16x32_bf16(ap, bv_, oacc[nf], 0, 0, 0);
            }
        }
    }

    int bb = bh >> 3, h = bh & 7;
#pragma unroll
    for (int nf = 0; nf < 2; nf++)
#pragma unroll
        for (int r = 0; r < 4; r++) {
            int m = bb * 4096 + q0 + hi * 4 + r;
            int c = h * 32 + nf * 16 + lo;
            O[m * 256 + c] = f2bf(oacc[nf][r] / lr[r]);
        }
}

// ---------------- out-proj + bias + residual + LayerNorm ----------------
__global__ __launch_bounds__(256) void proj_ln_kernel(const short* __restrict__ O,
                                                      const short* __restrict__ Wob,
                                                      const float* __restrict__ bo,
                                                      const short* __restrict__ Vres,
                                                      const float* __restrict__ gamma,
                                                      const float* __restrict__ beta,
                                                      float* __restrict__ out) {
    int wave = threadIdx.x >> 6, lane = threadIdx.x & 63;
    int lo = lane & 15, hi = lane >> 4;
    int m0 = blockIdx.x * 64 + wave * 16;

    f32x4 acc[16];
#pragma unroll
    for (int i = 0; i < 16; i++) acc[i] = (f32x4){0, 0, 0, 0};

    for (int ks = 0; ks < 8; ks++) {
        short8 a = *(const short8*)(O + (m0 + lo) * 256 + ks * 32 + hi * 8);
#pragma unroll
        for (int nf = 0; nf < 16; nf++) {
            short8 b = *(const short8*)(Wob + (nf * 16 + lo) * 256 + ks * 32 + hi * 8);
            acc[nf] = __builtin_amdgcn_mfma_f32_16x16x32_bf16(a, b, acc[nf], 0, 0, 0);
        }
    }
    // bias + residual in place
#pragma unroll
    for (int nf = 0; nf < 16; nf++)
#pragma unroll
        for (int r = 0; r < 4; r++) {
            int m = m0 + hi * 4 + r;
            int c = nf * 16 + lo;
            acc[nf][r] += bo[c] + bf2f(Vres[m * 256 + c]);
        }
    // LayerNorm per row (row = hi*4+r): 16 cols in-lane + 16-lane shuffle reduce
    float sum[4];
#pragma unroll
    for (int r = 0; r < 4; r++) {
        float t = 0.f;
#pragma unroll
        for (int nf = 0; nf < 16; nf++) t += acc[nf][r];
        sum[r] = t;
    }
#pragma unroll
    for (int d = 1; d < 16; d <<= 1)
#pragma unroll
        for (int r = 0; r < 4; r++) sum[r] += __shfl_xor(sum[r], d, 64);
    float mean[4];
#pragma unroll
    for (int r = 0; r < 4; r++) mean[r] = sum[r] * (1.0f / 256.0f);

    float ss[4];
#pragma unroll
    for (int r = 0; r < 4; r++) {
        float t = 0.f;
#pragma unroll
        for (int nf = 0; nf < 16; nf++) {
            float d_ = acc[nf][r] - mean[r];
            t += d_ * d_;
        }
        ss[r] = t;
    }
#pragma unroll
    for (int d = 1; d < 16; d <<= 1)
#pragma unroll
        for (int r = 0; r < 4; r++) ss[r] += __shfl_xor(ss[r], d, 64);
    float rstd[4];
#pragma unroll
    for (int r = 0; r < 4; r++) rstd[r] = rsqrtf(ss[r] * (1.0f / 256.0f) + 1e-6f);

#pragma unroll
    for (int nf = 0; nf < 16; nf++)
#pragma unroll
        for (int r = 0; r < 4; r++) {
            int m = m0 + hi * 4 + r;
            int c = nf * 16 + lo;
            out[m * 256 + c] = (acc[nf][r] - mean[r]) * rstd[r] * gamma[c] + beta[c];
        }
}

// ---------------- launcher ----------------
extern "C" void kernel_launch(void* const* d_in, const int* in_sizes, int n_in,
                              void* d_out, int out_size, void* d_ws, size_t ws_size,
                              hipStream_t stream) {
    const float* x     = (const float*)d_in[0];
    const float* Wq    = (const float*)d_in[1];
    const float* bq    = (const float*)d_in[2];
    const float* Wk    = (const float*)d_in[3];
    const float* bk    = (const float*)d_in[4];
    const float* Wv    = (const float*)d_in[5];
    const float* bv    = (const float*)d_in[6];
    const float* Wo    = (const float*)d_in[7];
    const float* bo    = (const float*)d_in[8];
    const float* gamma = (const float*)d_in[9];
    const float* beta  = (const float*)d_in[10];
    float* out = (float*)d_out;

    char* ws = (char*)d_ws;
    short* xb   = (short*)(ws);                 // [16384][256] bf16   8.39 MB
    short* Qb   = (short*)(ws + 8388608);       // [32][4096][32]      8.39 MB
    short* Kb   = (short*)(ws + 16777216);      // [32][4096][32]      8.39 MB
    short* Vt   = (short*)(ws + 25165824);      // [32][32][4096]      8.39 MB
    short* Vres = (short*)(ws + 33554432);      // [16384][256]        8.39 MB
    short* Ob   = (short*)(ws + 41943040);      // [16384][256]        8.39 MB
    short* Wb   = (short*)(ws + 50331648);      // [4][256][256] bf16  (q,k,v,o) 512 KB
    short* Wob  = Wb + 3 * 65536;

    conv_x_kernel<<<2048, 256, 0, stream>>>(x, xb, 524288);
    conv_w_kernel<<<dim3(32, 4), 256, 0, stream>>>(Wq, Wk, Wv, Wo, Wb);
    qkv_kernel<<<dim3(256, 3), 256, 0, stream>>>(xb, Wb, bq, bk, bv, Qb, Kb, Vt, Vres);
    attn_kernel<<<2048, 256, 0, stream>>>(Qb, Kb, Vt, Ob);
    proj_ln_kernel<<<256, 256, 0, stream>>>(Ob, Wob, bo, Vres, gamma, beta, out);
}

// Round 8
// 508.380 us; speedup vs baseline: 1.0140x; 1.0140x over previous
//
#include <hip/hip_runtime.h>
#include <hip/hip_bf16.h>
#include <math.h>

// Problem constants
#define NHD 8
#define DH 32
#define CC 256
#define NTOK 4096
#define BATCH 4
#define MTOT 16384

typedef __attribute__((ext_vector_type(8))) short short8;
typedef __attribute__((ext_vector_type(4))) short s16x4;
typedef __attribute__((ext_vector_type(4))) float f32x4;

#if __has_builtin(__builtin_amdgcn_exp2f)
#define EXP2F __builtin_amdgcn_exp2f
#else
#define EXP2F exp2f
#endif

__device__ inline float bf2f(short s) {
    unsigned int u = ((unsigned int)(unsigned short)s) << 16;
    float f; __builtin_memcpy(&f, &u, 4); return f;
}
__device__ inline short f2bf(float f) {
    __hip_bfloat16 h = __float2bfloat16(f);
    unsigned short u; __builtin_memcpy(&u, &h, 2); return (short)u;
}

// ---------------- conversion kernels ----------------
__global__ __launch_bounds__(256) void conv_x_kernel(const float* __restrict__ src,
                                                     short* __restrict__ dst, int n8) {
    int t = blockIdx.x * 256 + threadIdx.x;
    if (t >= n8) return;
    const f32x4* s4 = (const f32x4*)src;
    f32x4 a = s4[t * 2], b = s4[t * 2 + 1];
    short8 o;
    o[0] = f2bf(a[0]); o[1] = f2bf(a[1]); o[2] = f2bf(a[2]); o[3] = f2bf(a[3]);
    o[4] = f2bf(b[0]); o[5] = f2bf(b[1]); o[6] = f2bf(b[2]); o[7] = f2bf(b[3]);
    ((short8*)dst)[t] = o;
}

__global__ __launch_bounds__(256) void conv_w_kernel(const float* __restrict__ Wq,
                                                     const float* __restrict__ Wk,
                                                     const float* __restrict__ Wv,
                                                     const float* __restrict__ Wo,
                                                     short* __restrict__ dst) {
    int w = blockIdx.y;
    const float* src = (w == 0) ? Wq : (w == 1) ? Wk : (w == 2) ? Wv : Wo;
    int t = blockIdx.x * 256 + threadIdx.x;
    const f32x4* s4 = (const f32x4*)src;
    f32x4 a = s4[t * 2], b = s4[t * 2 + 1];
    short8 o;
    o[0] = f2bf(a[0]); o[1] = f2bf(a[1]); o[2] = f2bf(a[2]); o[3] = f2bf(a[3]);
    o[4] = f2bf(b[0]); o[5] = f2bf(b[1]); o[6] = f2bf(b[2]); o[7] = f2bf(b[3]);
    ((short8*)(dst + w * 65536))[t] = o;
}

// ---------------- QKV projection GEMM ----------------
// y = x @ W^T + b.  Q is additionally pre-scaled by (1/sqrt(dh))*log2(e) so the
// attention kernel can use exp2 directly with no per-element scale mul.
__global__ __launch_bounds__(256) void qkv_kernel(const short* __restrict__ xb,
                                                  const short* __restrict__ Wb,
                                                  const float* __restrict__ bq,
                                                  const float* __restrict__ bk,
                                                  const float* __restrict__ bv,
                                                  short* __restrict__ Qb,
                                                  short* __restrict__ Kb,
                                                  short* __restrict__ Vt,
                                                  short* __restrict__ Vres) {
    int wsel = blockIdx.y;
    const short* W = Wb + wsel * 65536;
    int wave = threadIdx.x >> 6;
    int lane = threadIdx.x & 63;
    int lo = lane & 15, hi = lane >> 4;
    int m0 = blockIdx.x * 64 + wave * 16;

    f32x4 acc[16];
#pragma unroll
    for (int i = 0; i < 16; i++) acc[i] = (f32x4){0, 0, 0, 0};

    for (int ks = 0; ks < 8; ks++) {
        short8 a = *(const short8*)(xb + (m0 + lo) * 256 + ks * 32 + hi * 8);
#pragma unroll
        for (int nf = 0; nf < 16; nf++) {
            short8 b = *(const short8*)(W + (nf * 16 + lo) * 256 + ks * 32 + hi * 8);
            acc[nf] = __builtin_amdgcn_mfma_f32_16x16x32_bf16(a, b, acc[nf], 0, 0, 0);
        }
    }
    const float* bias = (wsel == 0) ? bq : (wsel == 1) ? bk : bv;
    // qscale = (1/sqrt(32)) * log2(e)
    const float qscale = 0.17677669529663687f * 1.4426950408889634f;
#pragma unroll
    for (int nf = 0; nf < 16; nf++) {
#pragma unroll
        for (int r = 0; r < 4; r++) {
            int m = m0 + hi * 4 + r;
            int c = nf * 16 + lo;
            float v = acc[nf][r] + bias[c];
            int bb = m >> 12, n = m & 4095;
            int h = c >> 5, d = c & 31;
            int bh = bb * 8 + h;
            if (wsel == 0)      Qb[(bh * 4096 + n) * 32 + d] = f2bf(v * qscale);
            else if (wsel == 1) Kb[(bh * 4096 + n) * 32 + d] = f2bf(v);
            else {
                short s = f2bf(v);
                Vt[(bh * 32 + d) * 4096 + n] = s;   // transposed per head for PV A-operand
                Vres[m * 256 + c] = s;              // row-major for residual
            }
        }
    }
}

// ---------------- flash attention (swapped-operand, lane-local softmax) ----------------
// Grid: 32 (b,h) * 64 q-blocks = 2048 WGs. 4 waves, wave owns 16 q-rows. KV tile = 64.
// QK^T computed as S^T = mfma(K, Q): lane(lo,hi) holds S^T[kv=cf*16+hi*4+r][q=lo]
//   -> each lane owns ONE q-row; max/sum = in-lane tree + 2 shfl_xor (16,32).
// PV computed as O^T = mfma(Vt, P): C rows = d, cols = q=lo -> rescale/div use in-lane stats.
__global__ __launch_bounds__(256) void attn_kernel(const short* __restrict__ Qb,
                                                   const short* __restrict__ Kb,
                                                   const short* __restrict__ Vt,
                                                   short* __restrict__ O) {
    __shared__ short Pl[4][16][72];   // per-wave P tile [q=16][kv=64], stride 72 shorts (144B)
    int bx = blockIdx.x;
    int bh = bx >> 6;
    int qb = bx & 63;
    int wave = threadIdx.x >> 6, lane = threadIdx.x & 63;
    int lo = lane & 15, hi = lane >> 4;
    int q0 = qb * 64 + wave * 16;

    // Q fragment = B-operand (rows of Q -> C cols). Pre-scaled in qkv_kernel.
    short8 bq_ = *(const short8*)(Qb + (bh * 4096 + q0 + lo) * 32 + hi * 8);

    float mr = -1e30f, lr = 0.f;
    f32x4 oacc[2];   // oacc[nf][r] = O^T[d=nf*16+hi*4+r][q=lo]
    oacc[0] = (f32x4){0, 0, 0, 0};
    oacc[1] = (f32x4){0, 0, 0, 0};

    const short* Kbase = Kb + bh * 131072;
    const short* Vbase = Vt + bh * 131072;

    for (int kv = 0; kv < 4096; kv += 64) {
        // S^T tile: s[cf][r] = S'[kv + cf*16 + hi*4 + r][q0+lo]  (S' already in log2 units)
        f32x4 s[4];
#pragma unroll
        for (int cf = 0; cf < 4; cf++) {
            short8 ak = *(const short8*)(Kbase + (kv + cf * 16 + lo) * 32 + hi * 8);
            f32x4 z = (f32x4){0, 0, 0, 0};
            s[cf] = __builtin_amdgcn_mfma_f32_16x16x32_bf16(ak, bq_, z, 0, 0, 0);
        }

        // row max: in-lane tree over 16, then reduce across the 4 hi-lanes
        float t0 = fmaxf(fmaxf(s[0][0], s[0][1]), fmaxf(s[0][2], s[0][3]));
        float t1 = fmaxf(fmaxf(s[1][0], s[1][1]), fmaxf(s[1][2], s[1][3]));
        float t2 = fmaxf(fmaxf(s[2][0], s[2][1]), fmaxf(s[2][2], s[2][3]));
        float t3 = fmaxf(fmaxf(s[3][0], s[3][1]), fmaxf(s[3][2], s[3][3]));
        float mx = fmaxf(fmaxf(t0, t1), fmaxf(t2, t3));
        mx = fmaxf(mx, __shfl_xor(mx, 16, 64));
        mx = fmaxf(mx, __shfl_xor(mx, 32, 64));

        float mnew = fmaxf(mr, mx);
        float al = EXP2F(mr - mnew);
        mr = mnew;

        // P = exp2(S' - m)
        float p[4][4];
#pragma unroll
        for (int cf = 0; cf < 4; cf++)
#pragma unroll
            for (int r = 0; r < 4; r++) p[cf][r] = EXP2F(s[cf][r] - mnew);

        // row sum: in-lane tree + 2 shfl
        float u0 = (p[0][0] + p[0][1]) + (p[0][2] + p[0][3]);
        float u1 = (p[1][0] + p[1][1]) + (p[1][2] + p[1][3]);
        float u2 = (p[2][0] + p[2][1]) + (p[2][2] + p[2][3]);
        float u3 = (p[3][0] + p[3][1]) + (p[3][2] + p[3][3]);
        float rs = (u0 + u1) + (u2 + u3);
        rs += __shfl_xor(rs, 16, 64);
        rs += __shfl_xor(rs, 32, 64);

        lr = lr * al + rs;
        oacc[0][0] *= al; oacc[0][1] *= al; oacc[0][2] *= al; oacc[0][3] *= al;
        oacc[1][0] *= al; oacc[1][1] *= al; oacc[1][2] *= al; oacc[1][3] *= al;

        // P -> LDS, packed 4x bf16 (kv-consecutive in-lane), wave-private region.
        // Row q=lo, cols cf*16+hi*4 .. +3.  Same-wave RAW ordered by lgkmcnt.
#pragma unroll
        for (int cf = 0; cf < 4; cf++) {
            s16x4 pw;
            pw[0] = f2bf(p[cf][0]); pw[1] = f2bf(p[cf][1]);
            pw[2] = f2bf(p[cf][2]); pw[3] = f2bf(p[cf][3]);
            *(s16x4*)(&Pl[wave][lo][cf * 16 + hi * 4]) = pw;
        }

        // PV: O^T += Vt (A) x P (B).  b-frag = P[q=lo][kf*32 + hi*8 ..+7] (shared by nf).
#pragma unroll
        for (int kf = 0; kf < 2; kf++) {
            short8 pb = *(const short8*)(&Pl[wave][lo][kf * 32 + hi * 8]);
#pragma unroll
            for (int nf = 0; nf < 2; nf++) {
                short8 av = *(const short8*)(Vbase + (nf * 16 + lo) * 4096 + kv + kf * 32 + hi * 8);
                oacc[nf] = __builtin_amdgcn_mfma_f32_16x16x32_bf16(av, pb, oacc[nf], 0, 0, 0);
            }
        }
    }

    float inv = 1.0f / lr;
    int token = (bh >> 3) * 4096 + q0 + lo;
    int c0 = (bh & 7) * 32;
#pragma unroll
    for (int nf = 0; nf < 2; nf++) {
        s16x4 ow;
#pragma unroll
        for (int r = 0; r < 4; r++) ow[r] = f2bf(oacc[nf][r] * inv);
        *(s16x4*)(O + token * 256 + c0 + nf * 16 + hi * 4) = ow;
    }
}

// ---------------- out-proj + bias + residual + LayerNorm ----------------
__global__ __launch_bounds__(256) void proj_ln_kernel(const short* __restrict__ O,
                                                      const short* __restrict__ Wob,
                                                      const float* __restrict__ bo,
                                                      const short* __restrict__ Vres,
                                                      const float* __restrict__ gamma,
                                                      const float* __restrict__ beta,
                                                      float* __restrict__ out) {
    int wave = threadIdx.x >> 6, lane = threadIdx.x & 63;
    int lo = lane & 15, hi = lane >> 4;
    int m0 = blockIdx.x * 64 + wave * 16;

    f32x4 acc[16];
#pragma unroll
    for (int i = 0; i < 16; i++) acc[i] = (f32x4){0, 0, 0, 0};

    for (int ks = 0; ks < 8; ks++) {
        short8 a = *(const short8*)(O + (m0 + lo) * 256 + ks * 32 + hi * 8);
#pragma unroll
        for (int nf = 0; nf < 16; nf++) {
            short8 b = *(const short8*)(Wob + (nf * 16 + lo) * 256 + ks * 32 + hi * 8);
            acc[nf] = __builtin_amdgcn_mfma_f32_16x16x32_bf16(a, b, acc[nf], 0, 0, 0);
        }
    }
#pragma unroll
    for (int nf = 0; nf < 16; nf++)
#pragma unroll
        for (int r = 0; r < 4; r++) {
            int m = m0 + hi * 4 + r;
            int c = nf * 16 + lo;
            acc[nf][r] += bo[c] + bf2f(Vres[m * 256 + c]);
        }
    float sum[4];
#pragma unroll
    for (int r = 0; r < 4; r++) {
        float t = 0.f;
#pragma unroll
        for (int nf = 0; nf < 16; nf++) t += acc[nf][r];
        sum[r] = t;
    }
#pragma unroll
    for (int d = 1; d < 16; d <<= 1)
#pragma unroll
        for (int r = 0; r < 4; r++) sum[r] += __shfl_xor(sum[r], d, 64);
    float mean[4];
#pragma unroll
    for (int r = 0; r < 4; r++) mean[r] = sum[r] * (1.0f / 256.0f);

    float ss[4];
#pragma unroll
    for (int r = 0; r < 4; r++) {
        float t = 0.f;
#pragma unroll
        for (int nf = 0; nf < 16; nf++) {
            float d_ = acc[nf][r] - mean[r];
            t += d_ * d_;
        }
        ss[r] = t;
    }
#pragma unroll
    for (int d = 1; d < 16; d <<= 1)
#pragma unroll
        for (int r = 0; r < 4; r++) ss[r] += __shfl_xor(ss[r], d, 64);
    float rstd[4];
#pragma unroll
    for (int r = 0; r < 4; r++) rstd[r] = rsqrtf(ss[r] * (1.0f / 256.0f) + 1e-6f);

#pragma unroll
    for (int nf = 0; nf < 16; nf++)
#pragma unroll
        for (int r = 0; r < 4; r++) {
            int m = m0 + hi * 4 + r;
            int c = nf * 16 + lo;
            out[m * 256 + c] = (acc[nf][r] - mean[r]) * rstd[r] * gamma[c] + beta[c];
        }
}

// ---------------- launcher ----------------
extern "C" void kernel_launch(void* const* d_in, const int* in_sizes, int n_in,
                              void* d_out, int out_size, void* d_ws, size_t ws_size,
                              hipStream_t stream) {
    const float* x     = (const float*)d_in[0];
    const float* Wq    = (const float*)d_in[1];
    const float* bq    = (const float*)d_in[2];
    const float* Wk    = (const float*)d_in[3];
    const float* bk    = (const float*)d_in[4];
    const float* Wv    = (const float*)d_in[5];
    const float* bv    = (const float*)d_in[6];
    const float* Wo    = (const float*)d_in[7];
    const float* bo    = (const float*)d_in[8];
    const float* gamma = (const float*)d_in[9];
    const float* beta  = (const float*)d_in[10];
    float* out = (float*)d_out;

    char* ws = (char*)d_ws;
    short* xb   = (short*)(ws);                 // [16384][256] bf16   8.39 MB
    short* Qb   = (short*)(ws + 8388608);       // [32][4096][32]      8.39 MB
    short* Kb   = (short*)(ws + 16777216);      // [32][4096][32]      8.39 MB
    short* Vt   = (short*)(ws + 25165824);      // [32][32][4096]      8.39 MB
    short* Vres = (short*)(ws + 33554432);      // [16384][256]        8.39 MB
    short* Ob   = (short*)(ws + 41943040);      // [16384][256]        8.39 MB
    short* Wb   = (short*)(ws + 50331648);      // [4][256][256] bf16  (q,k,v,o) 512 KB
    short* Wob  = Wb + 3 * 65536;

    conv_x_kernel<<<2048, 256, 0, stream>>>(x, xb, 524288);
    conv_w_kernel<<<dim3(32, 4), 256, 0, stream>>>(Wq, Wk, Wv, Wo, Wb);
    qkv_kernel<<<dim3(256, 3), 256, 0, stream>>>(xb, Wb, bq, bk, bv, Qb, Kb, Vt, Vres);
    attn_kernel<<<2048, 256, 0, stream>>>(Qb, Kb, Vt, Ob);
    proj_ln_kernel<<<256, 256, 0, stream>>>(Ob, Wob, bo, Vres, gamma, beta, out);
}

// Round 14
// 348.542 us; speedup vs baseline: 1.4790x; 1.4586x over previous
//
#include <hip/hip_runtime.h>
#include <hip/hip_bf16.h>
#include <math.h>

// Problem constants
#define NHD 8
#define DH 32
#define CC 256
#define NTOK 4096
#define BATCH 4
#define MTOT 16384

typedef __attribute__((ext_vector_type(8))) short short8;
typedef __attribute__((ext_vector_type(4))) short s16x4;
typedef __attribute__((ext_vector_type(4))) float f32x4;
typedef __attribute__((ext_vector_type(16))) float f32x16;
typedef __attribute__((ext_vector_type(2))) unsigned int u32x2;

#if __has_builtin(__builtin_amdgcn_exp2f)
#define EXP2F __builtin_amdgcn_exp2f
#else
#define EXP2F exp2f
#endif

__device__ inline float bf2f(short s) {
    unsigned int u = ((unsigned int)(unsigned short)s) << 16;
    float f; __builtin_memcpy(&f, &u, 4); return f;
}
__device__ inline short f2bf(float f) {
    __hip_bfloat16 h = __float2bfloat16(f);
    unsigned short u; __builtin_memcpy(&u, &h, 2); return (short)u;
}
// pack two f32 -> one u32 of 2 bf16 (low = lo); plain C, compiler lowers well (m240)
__device__ inline unsigned int pack2(float lo, float hi) {
    unsigned int a = (unsigned short)f2bf(lo);
    unsigned int b = (unsigned short)f2bf(hi);
    return a | (b << 16);
}
__device__ inline short8 mk8(unsigned int a, unsigned int b, unsigned int c, unsigned int d) {
    unsigned int t[4] = {a, b, c, d};
    short8 r; __builtin_memcpy(&r, t, 16); return r;
}

// ---------------- conversion kernels ----------------
__global__ __launch_bounds__(256) void conv_x_kernel(const float* __restrict__ src,
                                                     short* __restrict__ dst, int n8) {
    int t = blockIdx.x * 256 + threadIdx.x;
    if (t >= n8) return;
    const f32x4* s4 = (const f32x4*)src;
    f32x4 a = s4[t * 2], b = s4[t * 2 + 1];
    short8 o;
    o[0] = f2bf(a[0]); o[1] = f2bf(a[1]); o[2] = f2bf(a[2]); o[3] = f2bf(a[3]);
    o[4] = f2bf(b[0]); o[5] = f2bf(b[1]); o[6] = f2bf(b[2]); o[7] = f2bf(b[3]);
    ((short8*)dst)[t] = o;
}

__global__ __launch_bounds__(256) void conv_w_kernel(const float* __restrict__ Wq,
                                                     const float* __restrict__ Wk,
                                                     const float* __restrict__ Wv,
                                                     const float* __restrict__ Wo,
                                                     short* __restrict__ dst) {
    int w = blockIdx.y;
    const float* src = (w == 0) ? Wq : (w == 1) ? Wk : (w == 2) ? Wv : Wo;
    int t = blockIdx.x * 256 + threadIdx.x;
    const f32x4* s4 = (const f32x4*)src;
    f32x4 a = s4[t * 2], b = s4[t * 2 + 1];
    short8 o;
    o[0] = f2bf(a[0]); o[1] = f2bf(a[1]); o[2] = f2bf(a[2]); o[3] = f2bf(a[3]);
    o[4] = f2bf(b[0]); o[5] = f2bf(b[1]); o[6] = f2bf(b[2]); o[7] = f2bf(b[3]);
    ((short8*)(dst + w * 65536))[t] = o;
}

// ---------------- QKV projection GEMM ----------------
// y = x @ W^T + b.  Q pre-scaled by (1/sqrt(dh))*log2(e) -> attn uses exp2 directly.
__global__ __launch_bounds__(256) void qkv_kernel(const short* __restrict__ xb,
                                                  const short* __restrict__ Wb,
                                                  const float* __restrict__ bq,
                                                  const float* __restrict__ bk,
                                                  const float* __restrict__ bv,
                                                  short* __restrict__ Qb,
                                                  short* __restrict__ Kb,
                                                  short* __restrict__ Vt,
                                                  short* __restrict__ Vres) {
    int wsel = blockIdx.y;
    const short* W = Wb + wsel * 65536;
    int wave = threadIdx.x >> 6;
    int lane = threadIdx.x & 63;
    int lo = lane & 15, hi = lane >> 4;
    int m0 = blockIdx.x * 64 + wave * 16;

    f32x4 acc[16];
#pragma unroll
    for (int i = 0; i < 16; i++) acc[i] = (f32x4){0, 0, 0, 0};

    for (int ks = 0; ks < 8; ks++) {
        short8 a = *(const short8*)(xb + (m0 + lo) * 256 + ks * 32 + hi * 8);
#pragma unroll
        for (int nf = 0; nf < 16; nf++) {
            short8 b = *(const short8*)(W + (nf * 16 + lo) * 256 + ks * 32 + hi * 8);
            acc[nf] = __builtin_amdgcn_mfma_f32_16x16x32_bf16(a, b, acc[nf], 0, 0, 0);
        }
    }
    const float* bias = (wsel == 0) ? bq : (wsel == 1) ? bk : bv;
    const float qscale = 0.17677669529663687f * 1.4426950408889634f;
#pragma unroll
    for (int nf = 0; nf < 16; nf++) {
#pragma unroll
        for (int r = 0; r < 4; r++) {
            int m = m0 + hi * 4 + r;
            int c = nf * 16 + lo;
            float v = acc[nf][r] + bias[c];
            int bb = m >> 12, n = m & 4095;
            int h = c >> 5, d = c & 31;
            int bh = bb * 8 + h;
            if (wsel == 0)      Qb[(bh * 4096 + n) * 32 + d] = f2bf(v * qscale);
            else if (wsel == 1) Kb[(bh * 4096 + n) * 32 + d] = f2bf(v);
            else {
                short s = f2bf(v);
                Vt[(bh * 32 + d) * 4096 + n] = s;   // transposed per head (PV A-operand)
                Vres[m * 256 + c] = s;              // row-major for residual
            }
        }
    }
}

// ---------------- flash attention v2b: 32x32 MFMA, in-register P, zero LDS ----------------
// Grid: 32 bh * 32 qblocks = 1024 WGs, 4 waves, wave owns 32 q-rows. KV tile = 32.
// S^T = mfma_32x32x16(K, Q) x2 (d-halves): lane owns q-col = lane&31, 16 kv vals
//   at rows (reg&3)+8*(reg>>2)+4*lh (lh = lane>>5). Softmax: in-lane tree + 1 shfl_xor(32).
// P relayout for PV B-operand via permlane32_swap builtin (or shfl_xor fallback):
//   partner lane^32 holds the complementary kv quads. O^T = mfma(V^T, P).
__global__ __launch_bounds__(256, 4) void attn_kernel(const short* __restrict__ Qb,
                                                      const short* __restrict__ Kb,
                                                      const short* __restrict__ Vt,
                                                      short* __restrict__ O) {
    int bx = blockIdx.x;
    int bh = bx >> 5;
    int qb = bx & 31;
    int wave = threadIdx.x >> 6, lane = threadIdx.x & 63;
    int l31 = lane & 31, lh = lane >> 5;
    int q0 = qb * 128 + wave * 32;

    const short* Qrow = Qb + (bh * 4096 + q0 + l31) * 32;
    short8 bq0 = *(const short8*)(Qrow + lh * 8);        // d 0-15 slice
    short8 bq1 = *(const short8*)(Qrow + 16 + lh * 8);   // d 16-31 slice

    const short* Kbase = Kb + bh * 131072;
    const short* Vrow  = Vt + (bh * 32 + l31) * 4096;    // A=V^T row d=l31

    float mr = -1e30f, lr = 0.f;
    f32x16 oacc;
#pragma unroll
    for (int i = 0; i < 16; i++) oacc[i] = 0.f;

    for (int kv0 = 0; kv0 < 4096; kv0 += 32) {
        const short* Krow = Kbase + (kv0 + l31) * 32;
        short8 ak0 = *(const short8*)(Krow + lh * 8);
        short8 ak1 = *(const short8*)(Krow + 16 + lh * 8);
        // V loads issued early; consumed after softmax
        short8 av0 = *(const short8*)(Vrow + kv0 + lh * 8);
        short8 av1 = *(const short8*)(Vrow + kv0 + 16 + lh * 8);

        f32x16 s;
#pragma unroll
        for (int i = 0; i < 16; i++) s[i] = 0.f;
        s = __builtin_amdgcn_mfma_f32_32x32x16_bf16(ak0, bq0, s, 0, 0, 0);
        s = __builtin_amdgcn_mfma_f32_32x32x16_bf16(ak1, bq1, s, 0, 0, 0);

        // row max: in-lane tree over 16 + cross-half
        float m0_ = fmaxf(fmaxf(s[0], s[1]), fmaxf(s[2], s[3]));
        float m1_ = fmaxf(fmaxf(s[4], s[5]), fmaxf(s[6], s[7]));
        float m2_ = fmaxf(fmaxf(s[8], s[9]), fmaxf(s[10], s[11]));
        float m3_ = fmaxf(fmaxf(s[12], s[13]), fmaxf(s[14], s[15]));
        float mx = fmaxf(fmaxf(m0_, m1_), fmaxf(m2_, m3_));
        mx = fmaxf(mx, __shfl_xor(mx, 32, 64));

        float mnew = fmaxf(mr, mx);
        float al = EXP2F(mr - mnew);
        mr = mnew;

        float p[16];
#pragma unroll
        for (int i = 0; i < 16; i++) p[i] = EXP2F(s[i] - mnew);

        float r0 = (p[0] + p[1]) + (p[2] + p[3]);
        float r1 = (p[4] + p[5]) + (p[6] + p[7]);
        float r2 = (p[8] + p[9]) + (p[10] + p[11]);
        float r3 = (p[12] + p[13]) + (p[14] + p[15]);
        float rs = (r0 + r1) + (r2 + r3);
        rs += __shfl_xor(rs, 32, 64);

        lr = lr * al + rs;
#pragma unroll
        for (int i = 0; i < 16; i++) oacc[i] *= al;

        // pack P to bf16 words; quad j covers kv = 8j + 4lh + {0..3}.
        unsigned int w0 = pack2(p[0], p[1]),   w1 = pack2(p[2], p[3]);
        unsigned int w2 = pack2(p[4], p[5]),   w3 = pack2(p[6], p[7]);
        unsigned int w4 = pack2(p[8], p[9]),   w5 = pack2(p[10], p[11]);
        unsigned int w6 = pack2(p[12], p[13]), w7 = pack2(p[14], p[15]);
        // Exchange with partner lane^32 to build kv-consecutive B-frags:
        // pb1 word0: lh0=w0(kv0,1), lh1=partner.w2(kv8,9);  word2: lh0=partner.w0(kv4,5), lh1=w2(kv12,13)
        short8 pb1, pb2;
#if __has_builtin(__builtin_amdgcn_permlane32_swap)
        u32x2 a0 = __builtin_amdgcn_permlane32_swap(w0, w2, false, false);
        u32x2 a1 = __builtin_amdgcn_permlane32_swap(w1, w3, false, false);
        u32x2 a2 = __builtin_amdgcn_permlane32_swap(w4, w6, false, false);
        u32x2 a3 = __builtin_amdgcn_permlane32_swap(w5, w7, false, false);
        pb1 = mk8(a0[0], a1[0], a0[1], a1[1]);   // P[kv0+0..15][q=l31], k=lh*8+j
        pb2 = mk8(a2[0], a3[0], a2[1], a3[1]);   // P[kv0+16..31][q=l31]
#else
        unsigned int x0 = __shfl_xor(w0, 32, 64), x1 = __shfl_xor(w1, 32, 64);
        unsigned int x2 = __shfl_xor(w2, 32, 64), x3 = __shfl_xor(w3, 32, 64);
        unsigned int x4 = __shfl_xor(w4, 32, 64), x5 = __shfl_xor(w5, 32, 64);
        unsigned int x6 = __shfl_xor(w6, 32, 64), x7 = __shfl_xor(w7, 32, 64);
        pb1 = mk8(lh ? x2 : w0, lh ? x3 : w1, lh ? w2 : x0, lh ? w3 : x1);
        pb2 = mk8(lh ? x6 : w4, lh ? x7 : w5, lh ? w6 : x4, lh ? w7 : x5);
#endif

        oacc = __builtin_amdgcn_mfma_f32_32x32x16_bf16(av0, pb1, oacc, 0, 0, 0);
        oacc = __builtin_amdgcn_mfma_f32_32x32x16_bf16(av1, pb2, oacc, 0, 0, 0);
    }

    float inv = 1.0f / lr;
    int token = (bh >> 3) * 4096 + q0 + l31;
    int c0 = (bh & 7) * 32 + 4 * lh;
#pragma unroll
    for (int j = 0; j < 4; j++) {
        s16x4 ow;
#pragma unroll
        for (int t = 0; t < 4; t++) ow[t] = f2bf(oacc[4 * j + t] * inv);
        *(s16x4*)(O + token * 256 + c0 + 8 * j) = ow;   // d = 8j + 4lh + t
    }
}

// ---------------- out-proj + bias + residual + LayerNorm ----------------
__global__ __launch_bounds__(256) void proj_ln_kernel(const short* __restrict__ O,
                                                      const short* __restrict__ Wob,
                                                      const float* __restrict__ bo,
                                                      const short* __restrict__ Vres,
                                                      const float* __restrict__ gamma,
                                                      const float* __restrict__ beta,
                                                      float* __restrict__ out) {
    int wave = threadIdx.x >> 6, lane = threadIdx.x & 63;
    int lo = lane & 15, hi = lane >> 4;
    int m0 = blockIdx.x * 64 + wave * 16;

    f32x4 acc[16];
#pragma unroll
    for (int i = 0; i < 16; i++) acc[i] = (f32x4){0, 0, 0, 0};

    for (int ks = 0; ks < 8; ks++) {
        short8 a = *(const short8*)(O + (m0 + lo) * 256 + ks * 32 + hi * 8);
#pragma unroll
        for (int nf = 0; nf < 16; nf++) {
            short8 b = *(const short8*)(Wob + (nf * 16 + lo) * 256 + ks * 32 + hi * 8);
            acc[nf] = __builtin_amdgcn_mfma_f32_16x16x32_bf16(a, b, acc[nf], 0, 0, 0);
        }
    }
#pragma unroll
    for (int nf = 0; nf < 16; nf++)
#pragma unroll
        for (int r = 0; r < 4; r++) {
            int m = m0 + hi * 4 + r;
            int c = nf * 16 + lo;
            acc[nf][r] += bo[c] + bf2f(Vres[m * 256 + c]);
        }
    float sum[4];
#pragma unroll
    for (int r = 0; r < 4; r++) {
        float t = 0.f;
#pragma unroll
        for (int nf = 0; nf < 16; nf++) t += acc[nf][r];
        sum[r] = t;
    }
#pragma unroll
    for (int d = 1; d < 16; d <<= 1)
#pragma unroll
        for (int r = 0; r < 4; r++) sum[r] += __shfl_xor(sum[r], d, 64);
    float mean[4];
#pragma unroll
    for (int r = 0; r < 4; r++) mean[r] = sum[r] * (1.0f / 256.0f);

    float ss[4];
#pragma unroll
    for (int r = 0; r < 4; r++) {
        float t = 0.f;
#pragma unroll
        for (int nf = 0; nf < 16; nf++) {
            float d_ = acc[nf][r] - mean[r];
            t += d_ * d_;
        }
        ss[r] = t;
    }
#pragma unroll
    for (int d = 1; d < 16; d <<= 1)
#pragma unroll
        for (int r = 0; r < 4; r++) ss[r] += __shfl_xor(ss[r], d, 64);
    float rstd[4];
#pragma unroll
    for (int r = 0; r < 4; r++) rstd[r] = rsqrtf(ss[r] * (1.0f / 256.0f) + 1e-6f);

#pragma unroll
    for (int nf = 0; nf < 16; nf++)
#pragma unroll
        for (int r = 0; r < 4; r++) {
            int m = m0 + hi * 4 + r;
            int c = nf * 16 + lo;
            out[m * 256 + c] = (acc[nf][r] - mean[r]) * rstd[r] * gamma[c] + beta[c];
        }
}

// ---------------- launcher ----------------
extern "C" void kernel_launch(void* const* d_in, const int* in_sizes, int n_in,
                              void* d_out, int out_size, void* d_ws, size_t ws_size,
                              hipStream_t stream) {
    const float* x     = (const float*)d_in[0];
    const float* Wq    = (const float*)d_in[1];
    const float* bq    = (const float*)d_in[2];
    const float* Wk    = (const float*)d_in[3];
    const float* bk    = (const float*)d_in[4];
    const float* Wv    = (const float*)d_in[5];
    const float* bv    = (const float*)d_in[6];
    const float* Wo    = (const float*)d_in[7];
    const float* bo    = (const float*)d_in[8];
    const float* gamma = (const float*)d_in[9];
    const float* beta  = (const float*)d_in[10];
    float* out = (float*)d_out;

    char* ws = (char*)d_ws;
    short* xb   = (short*)(ws);                 // [16384][256] bf16   8.39 MB
    short* Qb   = (short*)(ws + 8388608);       // [32][4096][32]      8.39 MB
    short* Kb   = (short*)(ws + 16777216);      // [32][4096][32]      8.39 MB
    short* Vt   = (short*)(ws + 25165824);      // [32][32][4096]      8.39 MB
    short* Vres = (short*)(ws + 33554432);      // [16384][256]        8.39 MB
    short* Ob   = (short*)(ws + 41943040);      // [16384][256]        8.39 MB
    short* Wb   = (short*)(ws + 50331648);      // [4][256][256] bf16  512 KB
    short* Wob  = Wb + 3 * 65536;

    conv_x_kernel<<<2048, 256, 0, stream>>>(x, xb, 524288);
    conv_w_kernel<<<dim3(32, 4), 256, 0, stream>>>(Wq, Wk, Wv, Wo, Wb);
    qkv_kernel<<<dim3(256, 3), 256, 0, stream>>>(xb, Wb, bq, bk, bv, Qb, Kb, Vt, Vres);
    attn_kernel<<<1024, 256, 0, stream>>>(Qb, Kb, Vt, Ob);
    proj_ln_kernel<<<256, 256, 0, stream>>>(Ob, Wob, bo, Vres, gamma, beta, out);
}